// Round 1
// baseline (1127.805 us; speedup 1.0000x reference)
//
#include <hip/hip_runtime.h>
#include <hip/hip_bf16.h>

#define NPIX (1024 * 1024)
#define HDIM 1024

// ---------------- union-find (device-wide, lock-free) ----------------
// Invariant: P[x] <= x always (union-by-min). Parents only decrease over
// time, and every value ever stored in P[x] is in x's component, so stale
// (L1-cached) reads are benign: extra hops, never wrong connectivity.
__device__ __forceinline__ int find_root(int* P, int x) {
    int p = P[x];
    while (p != x) {
        int gp = P[p];
        if (gp == p) return p;
        P[x] = gp;   // path compression, benign race
        x = gp;
        p = P[x];
    }
    return x;
}

__device__ __forceinline__ void unite(int* P, int a, int b) {
    int ra = find_root(P, a);
    int rb = find_root(P, b);
    while (ra != rb) {
        if (ra < rb) { int t = ra; ra = rb; rb = t; }   // ra = larger
        int old = atomicCAS(&P[ra], ra, rb);            // device-scope
        if (old == ra) return;
        ra = find_root(P, old);
        rb = find_root(P, rb);
    }
}

// ---------------- kernels ----------------
__global__ void init_k(int* __restrict__ P, float* __restrict__ inter,
                       float* __restrict__ uni, int total) {
    int g = blockIdx.x * blockDim.x + threadIdx.x;
    if (g >= total) return;
    P[g] = g;
    inter[g] = 0.f;
    uni[g] = 0.f;
}

__global__ void merge_k(const float* __restrict__ pred, const float* __restrict__ targ,
                        int* __restrict__ P, int total) {
    int g = blockIdx.x * blockDim.x + threadIdx.x;
    if (g >= total) return;
    float s = pred[g] + targ[g];
    if (!(s > 0.f)) return;
    int li = g & (NPIX - 1);
    int x = li & (HDIM - 1);
    int y = li >> 10;
    if (x + 1 < HDIM && (pred[g + 1] + targ[g + 1] > 0.f)) unite(P, g, g + 1);
    if (y + 1 < HDIM && (pred[g + HDIM] + targ[g + HDIM] > 0.f)) unite(P, g, g + HDIM);
}

// flatten + segmented accumulate: wave-level segmented scan over contiguous
// runs of equal root; only run-tail lanes issue atomics.
__global__ void accum_k(const float* __restrict__ pred, const float* __restrict__ targ,
                        int* __restrict__ P, float* __restrict__ inter,
                        float* __restrict__ uni, int total) {
    int g = blockIdx.x * blockDim.x + threadIdx.x;
    int lane = threadIdx.x & 63;
    int r = -1;
    float vi = 0.f, vu = 0.f;
    if (g < total) {
        float p = pred[g], t = targ[g];
        if (p + t > 0.f) {
            r = find_root(P, g);
            vi = p * t;
            vu = p + t;
        }
    }
    // head flags -> segment-start index (max-scan)
    int rprev = __shfl_up(r, 1);
    int segstart = (lane == 0 || r != rprev) ? lane : 0;
    #pragma unroll
    for (int d = 1; d < 64; d <<= 1) {
        int s = __shfl_up(segstart, d);
        if (lane >= d) segstart = max(segstart, s);
    }
    // clipped Hillis-Steele inclusive scan within each contiguous run
    #pragma unroll
    for (int d = 1; d < 64; d <<= 1) {
        float oi = __shfl_up(vi, d);
        float ou = __shfl_up(vu, d);
        if (lane - d >= segstart) { vi += oi; vu += ou; }
    }
    int rnext = __shfl_down(r, 1);
    bool tail = (lane == 63) || (r != rnext);
    if (r >= 0 && tail) {
        unsafeAtomicAdd(&inter[r], vi);   // HW global_atomic_add_f32
        unsafeAtomicAdd(&uni[r], vu);
    }
}

// per-root dice, block-reduced, one atomic per block per image
__global__ void dice_k(const float* __restrict__ inter, const float* __restrict__ uni,
                       float* __restrict__ sums, int b0, int total) {
    int g = blockIdx.x * blockDim.x + threadIdx.x;
    float ds = 0.f, dn = 0.f;
    if (g < total) {
        float u = uni[g];
        if (u > 0.f) {   // cnt>0 <=> union>0 (all masked terms strictly positive)
            ds = (2.f * inter[g] + 1e-6f) / (u + 1e-6f);
            dn = 1.f;
        }
    }
    #pragma unroll
    for (int d = 32; d > 0; d >>= 1) {
        ds += __shfl_down(ds, d);
        dn += __shfl_down(dn, d);
    }
    __shared__ float s_s[4], s_n[4];
    int wid = threadIdx.x >> 6;
    if ((threadIdx.x & 63) == 0) { s_s[wid] = ds; s_n[wid] = dn; }
    __syncthreads();
    if (threadIdx.x == 0) {
        float a = s_s[0] + s_s[1] + s_s[2] + s_s[3];
        float c = s_n[0] + s_n[1] + s_n[2] + s_n[3];
        if (a != 0.f || c != 0.f) {
            int img = b0 + (g >> 20);   // block never straddles images
            unsafeAtomicAdd(&sums[2 * img], a);
            unsafeAtomicAdd(&sums[2 * img + 1], c);
        }
    }
}

__global__ void zero_k(float* __restrict__ sums, int n) {
    int i = threadIdx.x;
    if (i < n) sums[i] = 0.f;
}

__global__ void final_k(const float* __restrict__ sums, float* __restrict__ out, int B) {
    if (threadIdx.x == 0 && blockIdx.x == 0) {
        float acc = 0.f;
        for (int b = 0; b < B; ++b) {
            float s = sums[2 * b], n = sums[2 * b + 1];
            acc += (n > 0.f) ? (1.f - s / n) : 1.f;
        }
        out[0] = acc / (float)B;
    }
}

// ---------------- launch ----------------
extern "C" void kernel_launch(void* const* d_in, const int* in_sizes, int n_in,
                              void* d_out, int out_size, void* d_ws, size_t ws_size,
                              hipStream_t stream) {
    const float* pred = (const float*)d_in[0];
    const float* targ = (const float*)d_in[1];
    float* out = (float*)d_out;
    int B = in_sizes[0] / NPIX;
    if (B < 1) B = 1;

    char* ws = (char*)d_ws;
    float* sums = (float*)ws;                       // 2*B floats
    const size_t base = 256;
    const size_t perImg = (size_t)NPIX * 12;        // P(4) + inter(4) + uni(4)

    int maxC = 1;
    if (ws_size > base + perImg) {
        size_t m = (ws_size - base) / perImg;
        maxC = (int)(m < (size_t)B ? m : (size_t)B);
        if (maxC < 1) maxC = 1;
    }

    int*   P     = (int*)  (ws + base);
    float* inter = (float*)(ws + base + (size_t)maxC * NPIX * 4);
    float* uni   = (float*)(ws + base + (size_t)maxC * NPIX * 8);

    zero_k<<<1, 64, 0, stream>>>(sums, 2 * B);

    for (int b0 = 0; b0 < B; b0 += maxC) {
        int C = (B - b0 < maxC) ? (B - b0) : maxC;
        int total = C * NPIX;
        int blocks = total / 256;
        const float* pc = pred + (size_t)b0 * NPIX;
        const float* tc = targ + (size_t)b0 * NPIX;
        init_k<<<blocks, 256, 0, stream>>>(P, inter, uni, total);
        merge_k<<<blocks, 256, 0, stream>>>(pc, tc, P, total);
        accum_k<<<blocks, 256, 0, stream>>>(pc, tc, P, inter, uni, total);
        dice_k<<<blocks, 256, 0, stream>>>(inter, uni, sums, b0, total);
    }

    final_k<<<1, 1, 0, stream>>>(sums, out, B);
}

// Round 2
// 320.353 us; speedup vs baseline: 3.5205x; 3.5205x over previous
//
#include <hip/hip_runtime.h>
#include <hip/hip_bf16.h>

#define NPIX (1024 * 1024)
#define HDIM 1024
#define BPI  512   // dice partial blocks per image

// ---------------- union-find (device-wide, lock-free) ----------------
// Invariant: P[x] <= x always (union-by-min). Parents only decrease over
// time, and every value ever stored in P[x] is in x's component, so stale
// reads are benign: extra hops, never wrong connectivity.
__device__ __forceinline__ int find_root(int* P, int x) {
    int p = P[x];
    while (p != x) {
        int gp = P[p];
        if (gp == p) return p;
        P[x] = gp;   // path compression, benign race
        x = gp;
        p = P[x];
    }
    return x;
}

__device__ __forceinline__ void unite(int* P, int a, int b) {
    int ra = find_root(P, a);
    int rb = find_root(P, b);
    while (ra != rb) {
        if (ra < rb) { int t = ra; ra = rb; rb = t; }   // ra = larger
        int old = atomicCAS(&P[ra], ra, rb);            // device-scope
        if (old == ra) return;
        ra = find_root(P, old);
        rb = find_root(P, rb);
    }
}

// ---------------- kernels ----------------
// vectorized init: 4 elements/thread
__global__ void init_k(int* __restrict__ P, float* __restrict__ inter,
                       float* __restrict__ uni, int total4) {
    int g = blockIdx.x * blockDim.x + threadIdx.x;
    if (g >= total4) return;
    int b = g * 4;
    int4 iv = make_int4(b, b + 1, b + 2, b + 3);
    *(int4*)(P + b) = iv;
    float4 z = make_float4(0.f, 0.f, 0.f, 0.f);
    *(float4*)(inter + b) = z;
    *(float4*)(uni + b) = z;
}

__global__ void merge_k(const float* __restrict__ pred, const float* __restrict__ targ,
                        int* __restrict__ P, int total) {
    int g = blockIdx.x * blockDim.x + threadIdx.x;
    if (g >= total) return;
    float s = pred[g] + targ[g];
    if (!(s > 0.f)) return;
    int li = g & (NPIX - 1);
    int x = li & (HDIM - 1);
    int y = li >> 10;
    if (x + 1 < HDIM && (pred[g + 1] + targ[g + 1] > 0.f)) unite(P, g, g + 1);
    if (y + 1 < HDIM && (pred[g + HDIM] + targ[g + HDIM] > 0.f)) unite(P, g, g + HDIM);
}

// flatten + segmented accumulate: wave-level segmented scan over contiguous
// runs of equal root; only run-tail lanes issue atomics.
__global__ void accum_k(const float* __restrict__ pred, const float* __restrict__ targ,
                        int* __restrict__ P, float* __restrict__ inter,
                        float* __restrict__ uni, int total) {
    int g = blockIdx.x * blockDim.x + threadIdx.x;
    int lane = threadIdx.x & 63;
    int r = -1;
    float vi = 0.f, vu = 0.f;
    if (g < total) {
        float p = pred[g], t = targ[g];
        if (p + t > 0.f) {
            r = find_root(P, g);
            vi = p * t;
            vu = p + t;
        }
    }
    // head flags -> segment-start index (max-scan)
    int rprev = __shfl_up(r, 1);
    int segstart = (lane == 0 || r != rprev) ? lane : 0;
    #pragma unroll
    for (int d = 1; d < 64; d <<= 1) {
        int s = __shfl_up(segstart, d);
        if (lane >= d) segstart = max(segstart, s);
    }
    // clipped Hillis-Steele inclusive scan within each contiguous run
    #pragma unroll
    for (int d = 1; d < 64; d <<= 1) {
        float oi = __shfl_up(vi, d);
        float ou = __shfl_up(vu, d);
        if (lane - d >= segstart) { vi += oi; vu += ou; }
    }
    int rnext = __shfl_down(r, 1);
    bool tail = (lane == 63) || (r != rnext);
    if (r >= 0 && tail) {
        unsafeAtomicAdd(&inter[r], vi);   // HW global_atomic_add_f32
        unsafeAtomicAdd(&uni[r], vu);
    }
}

// per-root dice partials: NO atomics. Block (img, blk) strides its image,
// block-reduces, writes exactly one partial pair. Deterministic.
__global__ void dice_part_k(const float* __restrict__ inter, const float* __restrict__ uni,
                            float* __restrict__ partials, int b0) {
    int img = blockIdx.x >> 9;          // /BPI
    int blk = blockIdx.x & (BPI - 1);
    const float* in = inter + (size_t)img * NPIX;
    const float* un = uni + (size_t)img * NPIX;
    float ds = 0.f, dn = 0.f;
    for (int i = blk * 256 + threadIdx.x; i < NPIX; i += BPI * 256) {
        float u = un[i];
        if (u > 0.f) {   // cnt>0 <=> union>0 (all masked terms strictly positive)
            ds += (2.f * in[i] + 1e-6f) / (u + 1e-6f);
            dn += 1.f;
        }
    }
    #pragma unroll
    for (int d = 32; d > 0; d >>= 1) {
        ds += __shfl_down(ds, d);
        dn += __shfl_down(dn, d);
    }
    __shared__ float s_s[4], s_n[4];
    int wid = threadIdx.x >> 6;
    if ((threadIdx.x & 63) == 0) { s_s[wid] = ds; s_n[wid] = dn; }
    __syncthreads();
    if (threadIdx.x == 0) {
        float a = s_s[0] + s_s[1] + s_s[2] + s_s[3];
        float c = s_n[0] + s_n[1] + s_n[2] + s_n[3];
        int idx = (b0 + img) * BPI + blk;
        partials[2 * idx] = a;
        partials[2 * idx + 1] = c;
    }
}

// per-image reduce of BPI partial pairs -> per-image loss (no atomics)
__global__ void reduce_k(const float* __restrict__ partials, float* __restrict__ imgloss) {
    int img = blockIdx.x;
    float s = 0.f, n = 0.f;
    for (int j = threadIdx.x; j < BPI; j += 256) {
        s += partials[2 * (img * BPI + j)];
        n += partials[2 * (img * BPI + j) + 1];
    }
    #pragma unroll
    for (int d = 32; d > 0; d >>= 1) {
        s += __shfl_down(s, d);
        n += __shfl_down(n, d);
    }
    __shared__ float s_s[4], s_n[4];
    int wid = threadIdx.x >> 6;
    if ((threadIdx.x & 63) == 0) { s_s[wid] = s; s_n[wid] = n; }
    __syncthreads();
    if (threadIdx.x == 0) {
        float a = s_s[0] + s_s[1] + s_s[2] + s_s[3];
        float c = s_n[0] + s_n[1] + s_n[2] + s_n[3];
        imgloss[img] = (c > 0.f) ? (1.f - a / c) : 1.f;
    }
}

__global__ void final_k(const float* __restrict__ imgloss, float* __restrict__ out, int B) {
    if (threadIdx.x == 0 && blockIdx.x == 0) {
        float acc = 0.f;
        for (int b = 0; b < B; ++b) acc += imgloss[b];
        out[0] = acc / (float)B;
    }
}

// ---------------- launch ----------------
extern "C" void kernel_launch(void* const* d_in, const int* in_sizes, int n_in,
                              void* d_out, int out_size, void* d_ws, size_t ws_size,
                              hipStream_t stream) {
    const float* pred = (const float*)d_in[0];
    const float* targ = (const float*)d_in[1];
    float* out = (float*)d_out;
    int B = in_sizes[0] / NPIX;
    if (B < 1) B = 1;

    char* ws = (char*)d_ws;
    float* imgloss  = (float*)ws;                           // B floats
    float* partials = (float*)(ws + 256);                   // B*BPI*2 floats
    size_t partBytes = (size_t)B * BPI * 2 * sizeof(float);
    size_t base = 256 + ((partBytes + 255) & ~(size_t)255);
    const size_t perImg = (size_t)NPIX * 12;                // P(4)+inter(4)+uni(4)

    int maxC = 1;
    if (ws_size > base + perImg) {
        size_t m = (ws_size - base) / perImg;
        maxC = (int)(m < (size_t)B ? m : (size_t)B);
        if (maxC < 1) maxC = 1;
    }

    int*   P     = (int*)  (ws + base);
    float* inter = (float*)(ws + base + (size_t)maxC * NPIX * 4);
    float* uni   = (float*)(ws + base + (size_t)maxC * NPIX * 8);

    for (int b0 = 0; b0 < B; b0 += maxC) {
        int C = (B - b0 < maxC) ? (B - b0) : maxC;
        int total = C * NPIX;
        int blocks = total / 256;
        const float* pc = pred + (size_t)b0 * NPIX;
        const float* tc = targ + (size_t)b0 * NPIX;
        init_k<<<total / 1024, 256, 0, stream>>>(P, inter, uni, total / 4);
        merge_k<<<blocks, 256, 0, stream>>>(pc, tc, P, total);
        accum_k<<<blocks, 256, 0, stream>>>(pc, tc, P, inter, uni, total);
        dice_part_k<<<C * BPI, 256, 0, stream>>>(inter, uni, partials, b0);
    }

    reduce_k<<<B, 256, 0, stream>>>(partials, imgloss);
    final_k<<<1, 1, 0, stream>>>(imgloss, out, B);
}

// Round 3
// 186.213 us; speedup vs baseline: 6.0565x; 1.7204x over previous
//
#include <hip/hip_runtime.h>
#include <hip/hip_bf16.h>

#define NPIX (1 << 20)
#define HDIM 1024
#define FRAG_PER_IMG 524288   // hard upper bound: 512 fragments/tile * 1024 tiles
#define NB_FRAG 64

// ---------------- union-find (works on global or LDS int*) ----------------
// Invariant: P[x] <= x (union-by-min). Parents only decrease; any stored value
// is in x's component, so stale reads are benign (extra hops, never wrong).
__device__ __forceinline__ int find_root(int* P, int x) {
    int p = P[x];
    while (p != x) {
        int gp = P[p];
        if (gp == p) return p;
        P[x] = gp;   // path compression, benign race
        x = gp;
        p = P[x];
    }
    return x;
}

__device__ __forceinline__ void unite(int* P, int a, int b) {
    int ra = find_root(P, a);
    int rb = find_root(P, b);
    while (ra != rb) {
        if (ra < rb) { int t = ra; ra = rb; rb = t; }   // ra = larger
        int old = atomicCAS(&P[ra], ra, rb);
        if (old == ra) return;
        ra = find_root(P, old);
        rb = find_root(P, rb);
    }
}

// ---------------- phase A: per-tile LDS CCL + fragment sums ----------------
// One block per 32x32 tile. LDS union-find over interior edges, LDS-atomic
// segmented sums per tile-fragment, write P for every pixel (root ptr or
// self), inter/uni ONLY at fragment-root indices, packed mask bits, and
// append fragment roots to a global list.
__global__ __launch_bounds__(256) void local_k(
        const float* __restrict__ pred, const float* __restrict__ targ,
        int* __restrict__ P, float* __restrict__ inter, float* __restrict__ uni,
        unsigned* __restrict__ mbits, int* __restrict__ fragRoot,
        int* __restrict__ fragCnt, int fragCap) {
    int tile = blockIdx.x;
    int img = tile >> 10;
    int ty = (tile >> 5) & 31, tx = tile & 31;
    int gbase = img * NPIX + ty * 32 * HDIM + tx * 32;
    __shared__ int s_lbl[1024];
    __shared__ float s_i[1024], s_u[1024];
    float pv[4], tv[4];
    #pragma unroll
    for (int k = 0; k < 4; ++k) {
        int li = threadIdx.x + k * 256;
        int g = gbase + (li >> 5) * HDIM + (li & 31);
        float p = pred[g], t = targ[g];
        pv[k] = p; tv[k] = t;
        s_lbl[li] = (p + t > 0.f) ? li : (li | 0x80000000);  // negative = unmasked
        s_i[li] = 0.f; s_u[li] = 0.f;
    }
    __syncthreads();
    // interior unions (right + down). Unmasked entries stay negative forever,
    // so the sign test on neighbors is race-free.
    #pragma unroll
    for (int k = 0; k < 4; ++k) {
        int li = threadIdx.x + k * 256;
        if (pv[k] + tv[k] > 0.f) {
            if ((li & 31) < 31 && s_lbl[li + 1] >= 0)  unite(s_lbl, li, li + 1);
            if (li < 992       && s_lbl[li + 32] >= 0) unite(s_lbl, li, li + 32);
        }
    }
    __syncthreads();
    // per-fragment sums via LDS atomics at the fragment root slot
    int rt[4]; bool isr[4]; int nroots = 0;
    #pragma unroll
    for (int k = 0; k < 4; ++k) {
        int li = threadIdx.x + k * 256;
        rt[k] = li; isr[k] = false;
        if (pv[k] + tv[k] > 0.f) {
            int r = find_root(s_lbl, li);
            rt[k] = r;
            atomicAdd(&s_i[r], pv[k] * tv[k]);
            atomicAdd(&s_u[r], pv[k] + tv[k]);
            if (r == li) { isr[k] = true; ++nroots; }
        }
    }
    __syncthreads();
    // writes: P for every px; inter/uni only at roots (rest never read)
    #pragma unroll
    for (int k = 0; k < 4; ++k) {
        int li = threadIdx.x + k * 256;
        int g = gbase + (li >> 5) * HDIM + (li & 31);
        int r = rt[k];
        int gr = gbase + (r >> 5) * HDIM + (r & 31);
        P[g] = (pv[k] + tv[k] > 0.f) ? gr : g;
        if (isr[k]) { inter[g] = s_i[li]; uni[g] = s_u[li]; }
    }
    // packed mask bits: one uint32 per tile row
    if (threadIdx.x < 32) {
        unsigned w = 0;
        #pragma unroll
        for (int lx = 0; lx < 32; ++lx)
            w |= (unsigned)(s_lbl[threadIdx.x * 32 + lx] >= 0) << lx;
        mbits[(img * HDIM + ty * 32 + threadIdx.x) * 32 + tx] = w;
    }
    // append fragment roots (block-aggregated, 1 global atomic per tile)
    __shared__ int s_cnt, s_base;
    if (threadIdx.x == 0) s_cnt = 0;
    __syncthreads();
    int myoff = 0;
    if (nroots) myoff = atomicAdd(&s_cnt, nroots);
    __syncthreads();
    if (threadIdx.x == 0) s_base = s_cnt ? atomicAdd(fragCnt, s_cnt) : 0;
    __syncthreads();
    if (nroots) {
        int o = s_base + myoff;
        #pragma unroll
        for (int k = 0; k < 4; ++k) {
            if (isr[k]) {
                int li = threadIdx.x + k * 256;
                if (o < fragCap)
                    fragRoot[o] = gbase + (li >> 5) * HDIM + (li & 31);
                ++o;
            }
        }
    }
}

// ---------------- phase B: boundary unions (only 63488 edges/image) --------
__global__ void bound_k(const unsigned* __restrict__ mbits, int* __restrict__ P) {
    int img = blockIdx.x / 248;
    int e = (blockIdx.x % 248) * 256 + threadIdx.x;   // 0 .. 63487
    int g1, g2;
    if (e < 31744) {            // vertical boundary: x = 32k+31 <-> x+1
        int k = e >> 10, y = e & 1023;
        unsigned w1 = mbits[(img * HDIM + y) * 32 + k];
        unsigned w2 = mbits[(img * HDIM + y) * 32 + k + 1];
        if (!(w1 >> 31) || !(w2 & 1)) return;
        g1 = img * NPIX + y * HDIM + k * 32 + 31;
        g2 = g1 + 1;
    } else {                    // horizontal boundary: y = 32k+31 <-> y+1
        int e2 = e - 31744;
        int k = e2 >> 10, x = e2 & 1023;
        int y = k * 32 + 31;
        unsigned w1 = mbits[(img * HDIM + y) * 32 + (x >> 5)];
        unsigned w2 = mbits[(img * HDIM + y + 1) * 32 + (x >> 5)];
        unsigned b = x & 31;
        if (!((w1 >> b) & 1) || !((w2 >> b) & 1)) return;
        g1 = img * NPIX + y * HDIM + x;
        g2 = g1 + HDIM;
    }
    unite(P, g1, g2);
}

// ---------------- phase C: fold donor fragments into final roots -----------
__global__ void merge_frag_k(const int* __restrict__ fragRoot, const int* __restrict__ fragCnt,
                             int* __restrict__ P, float* __restrict__ inter,
                             float* __restrict__ uni, int fragCap) {
    int n = fragCnt[0]; if (n > fragCap) n = fragCap;
    for (int i = blockIdx.x * blockDim.x + threadIdx.x; i < n;
         i += gridDim.x * blockDim.x) {
        int r0 = fragRoot[i];
        int r = find_root(P, r0);
        if (r != r0) {
            unsafeAtomicAdd(&inter[r], inter[r0]);
            unsafeAtomicAdd(&uni[r], uni[r0]);
        }
    }
}

// ---------------- phase D: dice over final roots, block partials -----------
__global__ void dice_frag_k(const int* __restrict__ fragRoot, const int* __restrict__ fragCnt,
                            int* __restrict__ P, const float* __restrict__ inter,
                            const float* __restrict__ uni,
                            float* __restrict__ partials, int b0, int B, int fragCap) {
    __shared__ float sb[8][2];
    if (threadIdx.x < 16) ((float*)sb)[threadIdx.x] = 0.f;
    __syncthreads();
    int n = fragCnt[0]; if (n > fragCap) n = fragCap;
    for (int i = blockIdx.x * blockDim.x + threadIdx.x; i < n;
         i += gridDim.x * blockDim.x) {
        int r0 = fragRoot[i];
        if (find_root(P, r0) != r0) continue;   // exactly one fragment per component is its root
        float u = uni[r0];
        float d = (2.f * inter[r0] + 1e-6f) / (u + 1e-6f);
        int ci = r0 >> 20;                      // chunk-local image
        atomicAdd(&sb[ci][0], d);
        atomicAdd(&sb[ci][1], 1.f);
    }
    __syncthreads();
    if (threadIdx.x < 16) {
        int ci = threadIdx.x >> 1, j = threadIdx.x & 1;
        int imgg = b0 + ci;
        if (imgg < B)
            partials[(blockIdx.x * B + imgg) * 2 + j] += ((float*)sb)[threadIdx.x];
    }
}

__global__ void zero_partials_k(float* __restrict__ p, int n) {
    int i = blockIdx.x * blockDim.x + threadIdx.x;
    if (i < n) p[i] = 0.f;
}
__global__ void zero_frag_k(int* __restrict__ fragCnt) {
    if (threadIdx.x == 0) fragCnt[0] = 0;
}

__global__ void final_k(const float* __restrict__ partials, float* __restrict__ out, int B) {
    __shared__ float sb[128][2];
    int t = threadIdx.x;
    if (t < 2 * B) {
        int img = t >> 1, j = t & 1;
        float a = 0.f;
        for (int bkt = 0; bkt < NB_FRAG; ++bkt) a += partials[(bkt * B + img) * 2 + j];
        sb[img][j] = a;
    }
    __syncthreads();
    if (t == 0) {
        float acc = 0.f;
        for (int img = 0; img < B; ++img) {
            float s = sb[img][0], nn = sb[img][1];
            acc += (nn > 0.f) ? (1.f - s / nn) : 1.f;
        }
        out[0] = acc / (float)B;
    }
}

// ---------------- launch ----------------
extern "C" void kernel_launch(void* const* d_in, const int* in_sizes, int n_in,
                              void* d_out, int out_size, void* d_ws, size_t ws_size,
                              hipStream_t stream) {
    const float* pred = (const float*)d_in[0];
    const float* targ = (const float*)d_in[1];
    float* out = (float*)d_out;
    int B = in_sizes[0] / NPIX;
    if (B < 1) B = 1;

    char* ws = (char*)d_ws;
    size_t off = 0;
    float* partials = (float*)(ws + off);
    off += ((size_t)NB_FRAG * B * 2 * sizeof(float) + 255) & ~(size_t)255;
    int* fragCnt = (int*)(ws + off);
    off += 256;
    size_t fixed = off;

    // per-image: P 4MB + inter 4MB + uni 4MB + mbits 128KB + frag 2MB
    const size_t perImg = (size_t)NPIX * 12 + (size_t)HDIM * 32 * 4
                        + (size_t)FRAG_PER_IMG * 4;
    int maxC = 1;
    if (ws_size > fixed + perImg) {
        size_t m = (ws_size - fixed) / perImg;
        maxC = (int)(m < (size_t)B ? m : (size_t)B);
        if (maxC < 1) maxC = 1;
        if (maxC > 8) maxC = 8;   // dice_frag buckets
    }
    int*      P        = (int*)     (ws + off); off += (size_t)maxC * NPIX * 4;
    float*    inter    = (float*)   (ws + off); off += (size_t)maxC * NPIX * 4;
    float*    uni      = (float*)   (ws + off); off += (size_t)maxC * NPIX * 4;
    unsigned* mbits    = (unsigned*)(ws + off); off += (size_t)maxC * HDIM * 32 * 4;
    int*      fragRoot = (int*)     (ws + off);

    zero_partials_k<<<(NB_FRAG * B * 2 + 255) / 256, 256, 0, stream>>>(
        partials, NB_FRAG * B * 2);

    for (int b0 = 0; b0 < B; b0 += maxC) {
        int C = (B - b0 < maxC) ? (B - b0) : maxC;
        const float* pc = pred + (size_t)b0 * NPIX;
        const float* tc = targ + (size_t)b0 * NPIX;
        int fragCap = C * FRAG_PER_IMG;
        zero_frag_k<<<1, 64, 0, stream>>>(fragCnt);
        local_k<<<C * 1024, 256, 0, stream>>>(pc, tc, P, inter, uni, mbits,
                                              fragRoot, fragCnt, fragCap);
        bound_k<<<C * 248, 256, 0, stream>>>(mbits, P);
        merge_frag_k<<<NB_FRAG, 256, 0, stream>>>(fragRoot, fragCnt, P, inter, uni, fragCap);
        dice_frag_k<<<NB_FRAG, 256, 0, stream>>>(fragRoot, fragCnt, P, inter, uni,
                                                 partials, b0, B, fragCap);
    }

    final_k<<<1, 256, 0, stream>>>(partials, out, B);
}

// Round 4
// 159.703 us; speedup vs baseline: 7.0619x; 1.1660x over previous
//
#include <hip/hip_runtime.h>
#include <hip/hip_bf16.h>

#define NPIX (1 << 20)
#define HDIM 1024
#define FRAG_PER_IMG 131072
#define NB_FRAG 64
#define RBIT 0x40000000

// ============ global union-find with slot-encoded roots ============
// P[px] for masked px: parent pixel index (strictly smaller), or RBIT|slot
// if px is a component root. Parents only decrease -> acyclic, termination
// guaranteed; stale reads benign (extra hops, never wrong connectivity).
__device__ __forceinline__ int find_root_g(int* P, int x) {
    for (;;) {
        int v = P[x];
        if ((v & RBIT) || v == x) return x;
        int vp = P[v];
        if ((vp & RBIT) || vp == v) return v;
        P[x] = vp;   // path halving, benign race (vp is a plain smaller pixel)
        x = vp;
    }
}

__device__ __forceinline__ void unite_g(int* P, int a, int b) {
    int ra = find_root_g(P, a);
    int rb = find_root_g(P, b);
    while (ra != rb) {
        if (ra < rb) { int t = ra; ra = rb; rb = t; }   // ra = larger pixel
        int exp = P[ra];
        if ((exp & RBIT) || exp == ra) {
            int old = atomicCAS(&P[ra], exp, rb);
            if (old == exp) return;
        }
        ra = find_root_g(P, ra);
        rb = find_root_g(P, rb);
    }
}

// ============ LDS union-find over run nodes (id = row*16 + k) ============
__device__ __forceinline__ int find_r(int* R, int n) {
    int p = R[n];
    while (p != n) {
        int gp = R[p];
        if (gp == p) return p;
        R[n] = gp;   // compression, benign race
        n = gp;
        p = R[n];
    }
    return n;
}

__device__ __forceinline__ void unite_r(int* R, int a, int b) {
    a = find_r(R, a); b = find_r(R, b);
    while (a != b) {
        if (a < b) { int t = a; a = b; b = t; }
        int old = atomicCAS(&R[a], a, b);
        if (old == a) return;
        a = find_r(R, old); b = find_r(R, b);
    }
}

// ============ phase A: per-tile run-based CCL ============
__global__ __launch_bounds__(256) void local_k(
        const float4* __restrict__ pred4, const float4* __restrict__ targ4,
        int* __restrict__ P, unsigned* __restrict__ mbits,
        int* __restrict__ fragRoot, float2* __restrict__ fragSums,
        int* __restrict__ fragCnt, int fragCap) {
    int tile = blockIdx.x;
    int img = tile >> 10;
    int ty = (tile >> 5) & 31, tx = tile & 31;
    int t = threadIdx.x;
    int r = t >> 3;        // tile row 0..31
    int xq = t & 7;        // quad within row
    int x0 = xq * 4;

    __shared__ unsigned s_mask[32], s_starts[32];
    __shared__ int s_ruf[512];
    __shared__ float s_i[512], s_u[512];
    __shared__ int s_cnt, s_base;

    if (t < 32) s_mask[t] = 0u;
    s_ruf[t] = t; s_ruf[t + 256] = t + 256;
    s_i[t] = 0.f; s_i[t + 256] = 0.f;
    s_u[t] = 0.f; s_u[t + 256] = 0.f;
    if (t == 0) s_cnt = 0;
    __syncthreads();

    // ---- load 4 px (float4), build row masks ----
    int rowg = img * HDIM + ty * 32 + r;          // global row index
    int q = rowg * 256 + tx * 8 + xq;             // float4 index
    float4 p4 = pred4[q], t4 = targ4[q];
    float sv[4] = {p4.x + t4.x, p4.y + t4.y, p4.z + t4.z, p4.w + t4.w};
    float iv[4] = {p4.x * t4.x, p4.y * t4.y, p4.z * t4.z, p4.w * t4.w};
    unsigned pm = 0;
    #pragma unroll
    for (int j = 0; j < 4; ++j) if (sv[j] > 0.f) pm |= 1u << j;
    if (pm) atomicOr(&s_mask[r], pm << x0);
    __syncthreads();

    if (t < 32) s_starts[t] = s_mask[t] & ~(s_mask[t] << 1);
    __syncthreads();

    // ---- run unions: one unite per vertical overlap interval ----
    if (t < 31) {
        unsigned o = s_mask[t] & s_mask[t + 1];
        unsigned os = o & ~(o << 1);
        unsigned sa = s_starts[t], sb = s_starts[t + 1];
        while (os) {
            int x = __ffs(os) - 1; os &= os - 1;
            unsigned below = (2u << x) - 1;
            int ka = __popc(sa & below) - 1;
            int kb = __popc(sb & below) - 1;
            unite_r(s_ruf, t * 16 + ka, (t + 1) * 16 + kb);
        }
    }
    __syncthreads();

    // ---- per-pack: root per pixel, P store, <=2 (root,sum) entries ----
    unsigned starts_r = s_starts[r];
    int pbase = rowg * HDIM + tx * 32 + x0;
    int rootA = -1, rootB = -1;
    float iA = 0.f, uA = 0.f, iB = 0.f, uB = 0.f;
    int pv[4];
    #pragma unroll
    for (int j = 0; j < 4; ++j) {
        if (pm & (1u << j)) {
            int xl = x0 + j;
            unsigned below = (2u << xl) - 1;
            int node = r * 16 + (__popc(starts_r & below) - 1);
            int root = find_r(s_ruf, node);
            int rr = root >> 4, rk = root & 15;
            unsigned sm = s_starts[rr];
            for (int z = 0; z < rk; ++z) sm &= sm - 1;
            int xr = __ffs(sm) - 1;
            int gr = (img * HDIM + ty * 32 + rr) * HDIM + tx * 32 + xr;
            pv[j] = gr;   // depth-1 pointer to component-min pixel
            if (rootA < 0 || root == rootA) { rootA = root; iA += iv[j]; uA += sv[j]; }
            else                            { rootB = root; iB += iv[j]; uB += sv[j]; }
        } else pv[j] = pbase + j;
    }
    *(int4*)(P + pbase) = make_int4(pv[0], pv[1], pv[2], pv[3]);

    // ---- segmented scan over 8-lane row groups, atomics only at tails ----
    int key; float kvi, kvu; bool hadA = false;
    if (rootB >= 0) {
        key = rootB; kvi = iB; kvu = uB; hadA = true;
        atomicAdd(&s_i[rootA], iA); atomicAdd(&s_u[rootA], uA);
    } else { key = rootA; kvi = (rootA >= 0) ? iA : 0.f; kvu = (rootA >= 0) ? uA : 0.f; }

    int lane = t & 63;
    int pkey = __shfl_up(key, 1);
    int head = ((lane & 7) == 0) || hadA || (key != pkey);
    int seg = head ? lane : 0;
    #pragma unroll
    for (int d = 1; d < 8; d <<= 1) {
        int s = __shfl_up(seg, d);
        if (lane >= d) seg = max(seg, s);
    }
    #pragma unroll
    for (int d = 1; d < 8; d <<= 1) {
        float oi = __shfl_up(kvi, d);
        float ou = __shfl_up(kvu, d);
        if (lane - d >= seg) { kvi += oi; kvu += ou; }
    }
    int nhead = __shfl_down(head, 1);
    bool tail = ((lane & 7) == 7) || nhead;
    if (key >= 0 && tail) { atomicAdd(&s_i[key], kvi); atomicAdd(&s_u[key], kvu); }
    __syncthreads();

    // ---- enumerate root runs -> fragment slots ----
    int myoff0 = -1, myoff1 = -1;
    {
        int n = t, rr = n >> 4, k = n & 15;
        if (k < __popc(s_starts[rr]) && s_ruf[n] == n) myoff0 = atomicAdd(&s_cnt, 1);
        n = t + 256; rr = n >> 4; k = n & 15;
        if (k < __popc(s_starts[rr]) && s_ruf[n] == n) myoff1 = atomicAdd(&s_cnt, 1);
    }
    __syncthreads();
    if (t == 0) s_base = (s_cnt > 0) ? atomicAdd(fragCnt, s_cnt) : 0;
    __syncthreads();
    #pragma unroll
    for (int z = 0; z < 2; ++z) {
        int off = z ? myoff1 : myoff0;
        if (off < 0) continue;
        int n = z ? (t + 256) : t;
        int rr = n >> 4, rk = n & 15;
        unsigned sm = s_starts[rr];
        for (int zz = 0; zz < rk; ++zz) sm &= sm - 1;
        int xr = __ffs(sm) - 1;
        int gr = (img * HDIM + ty * 32 + rr) * HDIM + tx * 32 + xr;
        int slot = s_base + off;
        if (slot < fragCap) {
            fragRoot[slot] = gr;
            fragSums[slot] = make_float2(s_i[n], s_u[n]);
            P[gr] = RBIT | slot;   // overwrites the self-pointer stored above
        }
    }
    if (t < 32) mbits[(img * HDIM + ty * 32 + t) * 32 + tx] = s_mask[t];
}

// ============ phase B: boundary unions (63488 edges/image) ============
__global__ void bound_k(const unsigned* __restrict__ mbits, int* __restrict__ P) {
    int img = blockIdx.x / 248;
    int e = (blockIdx.x % 248) * 256 + threadIdx.x;
    int g1, g2;
    if (e < 31744) {            // vertical boundary: x = 32k+31 <-> x+1
        int k = e >> 10, y = e & 1023;
        unsigned w1 = mbits[(img * HDIM + y) * 32 + k];
        unsigned w2 = mbits[(img * HDIM + y) * 32 + k + 1];
        if (!(w1 >> 31) || !(w2 & 1)) return;
        g1 = img * NPIX + y * HDIM + k * 32 + 31;
        g2 = g1 + 1;
    } else {                    // horizontal boundary: y = 32k+31 <-> y+1
        int e2 = e - 31744;
        int k = e2 >> 10, x = e2 & 1023;
        int y = k * 32 + 31;
        unsigned w1 = mbits[(img * HDIM + y) * 32 + (x >> 5)];
        unsigned w2 = mbits[(img * HDIM + y + 1) * 32 + (x >> 5)];
        unsigned b = x & 31;
        if (!((w1 >> b) & 1) || !((w2 >> b) & 1)) return;
        g1 = img * NPIX + y * HDIM + x;
        g2 = g1 + HDIM;
    }
    unite_g(P, g1, g2);
}

// ============ phase C: fold donor fragments into final roots ============
__global__ void merge_frag_k(const int* __restrict__ fragRoot, const int* __restrict__ fragCnt,
                             int* __restrict__ P, float* __restrict__ fragSums, int fragCap) {
    int n = fragCnt[0]; if (n > fragCap) n = fragCap;
    for (int i = blockIdx.x * blockDim.x + threadIdx.x; i < n;
         i += gridDim.x * blockDim.x) {
        int r0 = fragRoot[i];
        int r = find_root_g(P, r0);
        if (r != r0) {
            int v = P[r];
            if (v & RBIT) {
                int s = v & (RBIT - 1);
                float2 d = ((const float2*)fragSums)[i];
                unsafeAtomicAdd(&fragSums[2 * s], d.x);
                unsafeAtomicAdd(&fragSums[2 * s + 1], d.y);
            }
        }
    }
}

// ============ phase D: dice over final roots, block partials ============
__global__ void dice_frag_k(const int* __restrict__ fragRoot, const int* __restrict__ fragCnt,
                            const int* __restrict__ P, const float2* __restrict__ fragSums,
                            float* __restrict__ partials, int b0, int B, int fragCap) {
    __shared__ float sb[8][2];
    if (threadIdx.x < 16) ((float*)sb)[threadIdx.x] = 0.f;
    __syncthreads();
    int n = fragCnt[0]; if (n > fragCap) n = fragCap;
    for (int i = blockIdx.x * blockDim.x + threadIdx.x; i < n;
         i += gridDim.x * blockDim.x) {
        int r0 = fragRoot[i];
        if (!(P[r0] & RBIT)) continue;   // not a final root
        float2 su = fragSums[i];
        float d = (2.f * su.x + 1e-6f) / (su.y + 1e-6f);
        int ci = r0 >> 20;               // chunk-local image
        atomicAdd(&sb[ci][0], d);
        atomicAdd(&sb[ci][1], 1.f);
    }
    __syncthreads();
    if (threadIdx.x < 16) {
        int ci = threadIdx.x >> 1, j = threadIdx.x & 1;
        int imgg = b0 + ci;
        if (imgg < B)
            partials[(blockIdx.x * B + imgg) * 2 + j] += ((float*)sb)[threadIdx.x];
    }
}

__global__ void zero_partials_k(float* __restrict__ p, int n) {
    int i = blockIdx.x * blockDim.x + threadIdx.x;
    if (i < n) p[i] = 0.f;
}
__global__ void zero_frag_k(int* __restrict__ fragCnt) {
    if (threadIdx.x == 0) fragCnt[0] = 0;
}

__global__ void final_k(const float* __restrict__ partials, float* __restrict__ out, int B) {
    __shared__ float sb[128][2];
    int t = threadIdx.x;
    if (t < 2 * B) {
        int img = t >> 1, j = t & 1;
        float a = 0.f;
        for (int bkt = 0; bkt < NB_FRAG; ++bkt) a += partials[(bkt * B + img) * 2 + j];
        sb[img][j] = a;
    }
    __syncthreads();
    if (t == 0) {
        float acc = 0.f;
        for (int img = 0; img < B; ++img) {
            float s = sb[img][0], nn = sb[img][1];
            acc += (nn > 0.f) ? (1.f - s / nn) : 1.f;
        }
        out[0] = acc / (float)B;
    }
}

// ============ launch ============
extern "C" void kernel_launch(void* const* d_in, const int* in_sizes, int n_in,
                              void* d_out, int out_size, void* d_ws, size_t ws_size,
                              hipStream_t stream) {
    const float* pred = (const float*)d_in[0];
    const float* targ = (const float*)d_in[1];
    float* out = (float*)d_out;
    int B = in_sizes[0] / NPIX;
    if (B < 1) B = 1;

    char* ws = (char*)d_ws;
    size_t off = 0;
    float* partials = (float*)ws;
    off += ((size_t)NB_FRAG * B * 2 * sizeof(float) + 255) & ~(size_t)255;
    int* fragCnt = (int*)(ws + off);
    off += 256;
    size_t fixed = off;

    // per-image: P 4MB + mbits 128KB + fragRoot 512KB + fragSums 1MB
    const size_t perImg = (size_t)NPIX * 4 + (size_t)HDIM * 32 * 4
                        + (size_t)FRAG_PER_IMG * 4 + (size_t)FRAG_PER_IMG * 8;
    int maxC = 1;
    if (ws_size > fixed + perImg) {
        size_t m = (ws_size - fixed) / perImg;
        maxC = (int)(m < (size_t)B ? m : (size_t)B);
        if (maxC < 1) maxC = 1;
        if (maxC > 8) maxC = 8;
    }
    int*      P        = (int*)     (ws + off); off += (size_t)maxC * NPIX * 4;
    unsigned* mbits    = (unsigned*)(ws + off); off += (size_t)maxC * HDIM * 32 * 4;
    int*      fragRoot = (int*)     (ws + off); off += (size_t)maxC * FRAG_PER_IMG * 4;
    float2*   fragSums = (float2*)  (ws + off);

    zero_partials_k<<<(NB_FRAG * B * 2 + 255) / 256, 256, 0, stream>>>(
        partials, NB_FRAG * B * 2);

    for (int b0 = 0; b0 < B; b0 += maxC) {
        int C = (B - b0 < maxC) ? (B - b0) : maxC;
        const float* pc = pred + (size_t)b0 * NPIX;
        const float* tc = targ + (size_t)b0 * NPIX;
        int fragCap = C * FRAG_PER_IMG;
        zero_frag_k<<<1, 64, 0, stream>>>(fragCnt);
        local_k<<<C * 1024, 256, 0, stream>>>((const float4*)pc, (const float4*)tc,
                                              P, mbits, fragRoot, fragSums, fragCnt, fragCap);
        bound_k<<<C * 248, 256, 0, stream>>>(mbits, P);
        merge_frag_k<<<128, 256, 0, stream>>>(fragRoot, fragCnt, P, (float*)fragSums, fragCap);
        dice_frag_k<<<NB_FRAG, 256, 0, stream>>>(fragRoot, fragCnt, P, fragSums,
                                                 partials, b0, B, fragCap);
    }

    final_k<<<1, 256, 0, stream>>>(partials, out, B);
}